// Round 6
// baseline (415.278 us; speedup 1.0000x reference)
//
#include <hip/hip_runtime.h>

constexpr int D_IN  = 64;
constexpr int D_H1  = 32;
constexpr int D_H2  = 64;
constexpr int D_OUT = 128;
constexpr int NSEG  = 8192;

constexpr int BLOCK = 256;       // 4 waves
constexpr int RT    = 64;        // rows per tile
constexpr int NB    = 768;       // 3 blocks/CU x 256 CUs, persistent, balanced

typedef __bf16 bfx8 __attribute__((ext_vector_type(8)));
typedef __bf16 bfx4 __attribute__((ext_vector_type(4)));
typedef float  fx4  __attribute__((ext_vector_type(4)));

// MFMA 16x16x32 bf16 layouts (m89-verified):
//   A: m = lane&15, k = (lane>>4)*8 + j
//   B: n = lane&15, k = (lane>>4)*8 + i   (same lane->element map as A!)
//   D: row(m) = (lane>>4)*4 + reg, col(n) = lane&15
// L1/L2 swapped operands (W as A, h as B): lane holds 4 contiguous features
// of one data row -> bfx4 LDS writes. L3 unswapped: lane holds rows
// mt*16+quad*4+rg of cols wv*32+{j*16}+lr -> scanned DIRECTLY from registers.

// Raw barrier with LDS-only ordering: avoids __syncthreads' vmcnt(0) drain
// so prefetch global loads stay in flight across the barrier.
#define BAR_LGKM() do {                                        \
    asm volatile("s_waitcnt lgkmcnt(0)" ::: "memory");         \
    __builtin_amdgcn_s_barrier();                              \
    __builtin_amdgcn_sched_barrier(0);                         \
} while (0)

// Single barrier per tile. Buffer slots: sf/sh2 x2, sseg x3.
// Max wave skew is 1 iteration (the barrier), so:
//   sf[i&1]   read pre-BAR(i),  written for i+1 pre-BAR(i)   -> 2 slots safe
//   sh2[i&1]  read post-BAR(i), written for i+1 pre-BAR(i+1) -> 2 slots safe
//   sseg[i%3] read post-BAR(i) (scan), written for i+2 pre-BAR(i+2) -> 3 slots
__global__ __launch_bounds__(BLOCK, 3) void mlp_seg_mfma(
    const float* __restrict__ f, const int* __restrict__ seg,
    const float* __restrict__ W1, const float* __restrict__ b1,
    const float* __restrict__ W2, const float* __restrict__ b2,
    const float* __restrict__ W3, const float* __restrict__ b3,
    float* __restrict__ sums, float* __restrict__ counts,
    int N, int ntiles)
{
    __shared__ __align__(16) __bf16 sf [2][RT * 64]; // 16 KB
    __shared__ __align__(16) __bf16 sh1[RT * 32];    // 4 KB (wave-private rows)
    __shared__ __align__(16) __bf16 sh2[2][RT * 64]; // 16 KB
    __shared__ __align__(16) int sseg3[3][RT];       // 768 B

    const int tid  = threadIdx.x;
    const int wv   = tid >> 6;
    const int lane = tid & 63;
    const int lr   = lane & 15;
    const int quad = lane >> 4;
    const int m0   = wv * 16;          // this wave's 16-row slice for L1/L2
    const int ar   = m0 + lr;          // data row for this lane (L1/L2)

    // ---- weight fragments + biases -> registers (one-time, L2-cached) ----
    bfx8 fw1[2][2];                    // W1[64][32]
    #pragma unroll
    for (int j = 0; j < 2; ++j)
        #pragma unroll
        for (int ks = 0; ks < 2; ++ks)
            #pragma unroll
            for (int i = 0; i < 8; ++i)
                fw1[j][ks][i] = (__bf16)W1[(ks*32 + quad*8 + i)*D_H1 + j*16 + lr];

    bfx8 fw2[4];                       // W2[32][64], K=32 single step
    #pragma unroll
    for (int j = 0; j < 4; ++j)
        #pragma unroll
        for (int i = 0; i < 8; ++i)
            fw2[j][i] = (__bf16)W2[(quad*8 + i)*D_H2 + j*16 + lr];

    bfx8 fw3[2][2];                    // W3[64][128], cols wv*32 + j*16 + lr
    #pragma unroll
    for (int j = 0; j < 2; ++j)
        #pragma unroll
        for (int ks = 0; ks < 2; ++ks)
            #pragma unroll
            for (int i = 0; i < 8; ++i)
                fw3[j][ks][i] = (__bf16)W3[(ks*32 + quad*8 + i)*D_OUT + wv*32 + j*16 + lr];

    // biases per-lane for swapped-D layout: feature = j*16 + quad*4 + rg
    fx4 rb1v[2], rb2v[4];
    #pragma unroll
    for (int j = 0; j < 2; ++j)
        #pragma unroll
        for (int rg = 0; rg < 4; ++rg) rb1v[j][rg] = b1[j*16 + quad*4 + rg];
    #pragma unroll
    for (int j = 0; j < 4; ++j)
        #pragma unroll
        for (int rg = 0; rg < 4; ++rg) rb2v[j][rg] = b2[j*16 + quad*4 + rg];
    float rb3[2];                      // folded in at flush time (run_len * b3)
    #pragma unroll
    for (int j = 0; j < 2; ++j) rb3[j] = b3[wv*32 + j*16 + lr];

    // ---- persistent segment-run state: lane owns cols {col0, col0+16},
    //      rows mt*16+quad*4+rg (16 rows/tile, increasing order) ----
    const int  col0    = wv*32 + lr;
    const bool cntlane = (wv == 0) && (lr == 0);  // 4 lanes, quads cover all 64 rows
    int   cur_seg = -1;
    float rs0 = 0.f, rs1 = 0.f;
    int   rlen = 0;

    // ---- balanced contiguous tile ranges over persistent blocks ----
    const int nb   = gridDim.x;
    const int bb   = blockIdx.x;
    const int base = ntiles / nb, rem = ntiles % nb;
    const int tstart = bb * base + min(bb, rem);
    const int cnt    = base + (bb < rem ? 1 : 0);

    // ---- prologue: stage tile tstart into slot 0 ----
    if (cnt > 0) {
        const int R0 = tstart * RT;
        const float4* f4 = (const float4*)f + (size_t)R0 * 16;
        #pragma unroll
        for (int i = 0; i < 4; ++i) {
            const int idx4 = tid + i * 256;
            float4 qq = make_float4(0.f, 0.f, 0.f, 0.f);
            if ((size_t)R0 * 64 + (size_t)idx4 * 4 < (size_t)N * 64) qq = f4[idx4];
            const int r = idx4 >> 4;
            const int c = (idx4 & 15) * 4;
            bfx4 v;
            v[0] = (__bf16)qq.x; v[1] = (__bf16)qq.y;
            v[2] = (__bf16)qq.z; v[3] = (__bf16)qq.w;
            *(bfx4*)&sf[0][r*64 + (((c >> 3) ^ (r & 7)) << 3) + (c & 7)] = v;
        }
        if (tid < RT) sseg3[0][tid] = (R0 + tid < N) ? seg[R0 + tid] : -2;
    }
    __syncthreads();

    int p3 = 0;                        // sseg slot for current tile
    for (int i = 0; i < cnt; ++i) {
        const int t  = tstart + i;
        const int p2 = i & 1;
        const int p3n = (p3 + 1 == 3) ? 0 : p3 + 1;
        const bool havenext = (i + 1 < cnt);

        // ---- issue next tile's global loads EARLY ----
        float4 q[4];
        int rseg = -2;
        if (havenext) {
            const int Rn = (t + 1) * RT;
            const float4* f4n = (const float4*)f + (size_t)Rn * 16;
            #pragma unroll
            for (int k = 0; k < 4; ++k) {
                const int idx4 = tid + k * 256;
                q[k] = make_float4(0.f, 0.f, 0.f, 0.f);
                if ((size_t)Rn * 64 + (size_t)idx4 * 4 < (size_t)N * 64)
                    q[k] = f4n[idx4];
            }
            if (tid < RT) rseg = (Rn + tid < N) ? seg[Rn + tid] : -2;
        }

        // ---- L1: h1^T = W1^T * f^T (swapped), rows m0..m0+15 ----
        fx4 acc1[2] = {{0,0,0,0},{0,0,0,0}};
        #pragma unroll
        for (int ks = 0; ks < 2; ++ks) {
            bfx8 a = *(const bfx8*)&sf[p2][ar*64 + (((ks*4 + quad) ^ (ar & 7)) << 3)];
            #pragma unroll
            for (int j = 0; j < 2; ++j)
                acc1[j] = __builtin_amdgcn_mfma_f32_16x16x32_bf16(fw1[j][ks], a, acc1[j], 0, 0, 0);
        }
        #pragma unroll
        for (int j = 0; j < 2; ++j) {
            bfx4 w;
            #pragma unroll
            for (int rg = 0; rg < 4; ++rg)
                w[rg] = (__bf16)fmaxf(acc1[j][rg] + rb1v[j][rg], 0.f);
            const int b = j*2 + (quad >> 1);
            *(bfx4*)&sh1[ar*32 + ((b ^ (ar & 3)) << 3) + (quad & 1)*4] = w;
        }
        // no barrier: sh1 rows [m0, m0+16) written and read by this wave only

        // ---- L2: h2^T = W2^T * h1^T (swapped), K=32 ----
        fx4 acc2[4] = {{0,0,0,0},{0,0,0,0},{0,0,0,0},{0,0,0,0}};
        {
            bfx8 a = *(const bfx8*)&sh1[ar*32 + ((quad ^ (ar & 3)) << 3)];
            #pragma unroll
            for (int j = 0; j < 4; ++j)
                acc2[j] = __builtin_amdgcn_mfma_f32_16x16x32_bf16(fw2[j], a, acc2[j], 0, 0, 0);
        }
        #pragma unroll
        for (int j = 0; j < 4; ++j) {
            bfx4 w;
            #pragma unroll
            for (int rg = 0; rg < 4; ++rg)
                w[rg] = (__bf16)fmaxf(acc2[j][rg] + rb2v[j][rg], 0.f);
            const int b = j*2 + (quad >> 1);
            *(bfx4*)&sh2[p2][ar*64 + ((b ^ (ar & 7)) << 3) + (quad & 1)*4] = w;
        }

        // ---- stage next tile (pre-barrier; vmcnt waits inserted on q use) ----
        if (havenext) {
            #pragma unroll
            for (int k = 0; k < 4; ++k) {
                const int idx4 = tid + k * 256;
                const int r = idx4 >> 4;
                const int c = (idx4 & 15) * 4;
                bfx4 v;
                v[0] = (__bf16)q[k].x; v[1] = (__bf16)q[k].y;
                v[2] = (__bf16)q[k].z; v[3] = (__bf16)q[k].w;
                *(bfx4*)&sf[p2 ^ 1][r*64 + (((c >> 3) ^ (r & 7)) << 3) + (c & 7)] = v;
            }
            if (tid < RT) sseg3[p3n][tid] = rseg;
        }

        BAR_LGKM();   // sh2 + next-sf + next-sseg visible; ONLY barrier per tile

        // ---- L3: wave-owned 32-col slab over ALL 64 rows; acc3 stays live ----
        fx4 acc3[4][2];
        #pragma unroll
        for (int mt = 0; mt < 4; ++mt) {
            acc3[mt][0] = (fx4){0,0,0,0};
            acc3[mt][1] = (fx4){0,0,0,0};
            const int arow = mt*16 + lr;
            #pragma unroll
            for (int ks = 0; ks < 2; ++ks) {
                bfx8 a = *(const bfx8*)&sh2[p2][arow*64 + (((ks*4 + quad) ^ (arow & 7)) << 3)];
                #pragma unroll
                for (int j = 0; j < 2; ++j)
                    acc3[mt][j] = __builtin_amdgcn_mfma_f32_16x16x32_bf16(a, fw3[j][ks], acc3[mt][j], 0, 0, 0);
            }
        }

        // ---- segment scan DIRECTLY from registers (f32, no LDS round-trip).
        //      Lane's rows: mt*16 + quad*4 + rg, increasing; sorted seg ids
        //      => per-lane subsequence sorted; partial runs merge via atomics.
        #pragma unroll
        for (int mt = 0; mt < 4; ++mt) {
            const int4 s4 = *(const int4*)&sseg3[p3][mt*16 + quad*4];
            const int ss[4] = {s4.x, s4.y, s4.z, s4.w};
            #pragma unroll
            for (int rg = 0; rg < 4; ++rg) {
                const int s = ss[rg];
                if (s != cur_seg) {
                    if (cur_seg >= 0) {
                        atomicAdd(&sums[(size_t)cur_seg * D_OUT + col0],      rs0 + (float)rlen * rb3[0]);
                        atomicAdd(&sums[(size_t)cur_seg * D_OUT + col0 + 16], rs1 + (float)rlen * rb3[1]);
                        if (cntlane) atomicAdd(&counts[cur_seg], (float)rlen);
                    }
                    cur_seg = s; rs0 = 0.f; rs1 = 0.f; rlen = 0;
                }
                rs0 += acc3[mt][0][rg];
                rs1 += acc3[mt][1][rg];
                ++rlen;
            }
        }
        p3 = p3n;
    }

    if (cur_seg >= 0) {
        atomicAdd(&sums[(size_t)cur_seg * D_OUT + col0],      rs0 + (float)rlen * rb3[0]);
        atomicAdd(&sums[(size_t)cur_seg * D_OUT + col0 + 16], rs1 + (float)rlen * rb3[1]);
        if (cntlane) atomicAdd(&counts[cur_seg], (float)rlen);
    }
}

__global__ __launch_bounds__(256) void div_kernel(
    const float* __restrict__ sums, const float* __restrict__ counts,
    float* __restrict__ out, int total)
{
    const int i = blockIdx.x * 256 + threadIdx.x;
    if (i < total) out[i] = sums[i] / fmaxf(counts[i >> 7], 1.f);
}

extern "C" void kernel_launch(void* const* d_in, const int* in_sizes, int n_in,
                              void* d_out, int out_size, void* d_ws, size_t ws_size,
                              hipStream_t stream) {
    const float* f   = (const float*)d_in[0];
    const int*   seg = (const int*)  d_in[1];
    const float* W1 = (const float*)d_in[3];
    const float* b1 = (const float*)d_in[4];
    const float* W2 = (const float*)d_in[5];
    const float* b2 = (const float*)d_in[6];
    const float* W3 = (const float*)d_in[7];
    const float* b3 = (const float*)d_in[8];
    float* out = (float*)d_out;

    const int N = in_sizes[0] / D_IN;

    float* sums   = (float*)d_ws;                 // [NSEG * D_OUT]
    float* counts = sums + (size_t)NSEG * D_OUT;  // [NSEG]

    hipMemsetAsync(d_ws, 0, ((size_t)NSEG * D_OUT + NSEG) * sizeof(float), stream);

    const int ntiles  = (N + RT - 1) / RT;
    const int nblocks = min(NB, ntiles);
    mlp_seg_mfma<<<nblocks, BLOCK, 0, stream>>>(f, seg, W1, b1, W2, b2, W3, b3,
                                                sums, counts, N, ntiles);

    const int total = NSEG * D_OUT;
    div_kernel<<<(total + 255) / 256, 256, 0, stream>>>(sums, counts, out, total);
}

// Round 7
// 410.734 us; speedup vs baseline: 1.0111x; 1.0111x over previous
//
#include <hip/hip_runtime.h>

constexpr int D_IN  = 64;
constexpr int D_H1  = 32;
constexpr int D_H2  = 64;
constexpr int D_OUT = 128;
constexpr int NSEG  = 8192;

constexpr int BLOCK = 256;       // 4 waves
constexpr int RT    = 64;        // rows per tile
constexpr int NB    = 768;       // 3 blocks/CU x 256 CUs, persistent, balanced

typedef __bf16 bfx8 __attribute__((ext_vector_type(8)));
typedef __bf16 bfx4 __attribute__((ext_vector_type(4)));
typedef float  fx4  __attribute__((ext_vector_type(4)));

// Opaque keep-alive: the asm's output cannot be rematerialized/sunk, so the
// value MUST stay in registers across the tile loop (VGPR 84 in r6 proved the
// compiler otherwise re-loads weight fragments from global EVERY tile).
#define PIN(v) asm volatile("" : "+v"(v))

// MFMA 16x16x32 bf16 layouts (m89-verified):
//   A: m = lane&15, k = (lane>>4)*8 + j
//   B: n = lane&15, k = (lane>>4)*8 + i   (same lane->element map as A!)
//   D: row(m) = (lane>>4)*4 + reg, col(n) = lane&15
// L1/L2 swapped operands (W as A, h as B): lane holds 4 contiguous features
// of one data row -> bfx4 LDS writes. L3 unswapped: lane holds rows
// mt*16+quad*4+rg of cols wv*32+{j*16}+lr -> scanned DIRECTLY from registers.

// Raw barrier with LDS-only ordering: avoids __syncthreads' vmcnt(0) drain
// so prefetch global loads stay in flight across the barrier.
#define BAR_LGKM() do {                                        \
    asm volatile("s_waitcnt lgkmcnt(0)" ::: "memory");         \
    __builtin_amdgcn_s_barrier();                              \
    __builtin_amdgcn_sched_barrier(0);                         \
} while (0)

// ---- weight repack: fragment-ordered bf16 so each (lane, frag) is ONE
//      aligned 16B load in the main kernel. Layout (bfx8 units):
//      [0..255]    fw1 frag (j*2+ks)*64 + lane
//      [256..511]  fw2 frag j*64 + lane
//      [512..1535] fw3 frag ((wv*2+j)*2+ks)*64 + lane
__global__ __launch_bounds__(256) void repack_w(
    const float* __restrict__ W1, const float* __restrict__ W2,
    const float* __restrict__ W3, __bf16* __restrict__ wp)
{
    const int tid  = threadIdx.x;
    const int lane = tid & 63, wv = tid >> 6;
    const int lr   = lane & 15, quad = lane >> 4;
    #pragma unroll
    for (int j = 0; j < 2; ++j)
        #pragma unroll
        for (int ks = 0; ks < 2; ++ks) {
            bfx8 v;
            #pragma unroll
            for (int i = 0; i < 8; ++i)
                v[i] = (__bf16)W3[(ks*32 + quad*8 + i)*D_OUT + wv*32 + j*16 + lr];
            *(bfx8*)&wp[(512 + ((wv*2 + j)*2 + ks)*64 + lane) * 8] = v;
        }
    if (wv == 0) {
        #pragma unroll
        for (int j = 0; j < 2; ++j)
            #pragma unroll
            for (int ks = 0; ks < 2; ++ks) {
                bfx8 v;
                #pragma unroll
                for (int i = 0; i < 8; ++i)
                    v[i] = (__bf16)W1[(ks*32 + quad*8 + i)*D_H1 + j*16 + lr];
                *(bfx8*)&wp[((j*2 + ks)*64 + lane) * 8] = v;
            }
        #pragma unroll
        for (int j = 0; j < 4; ++j) {
            bfx8 v;
            #pragma unroll
            for (int i = 0; i < 8; ++i)
                v[i] = (__bf16)W2[(quad*8 + i)*D_H2 + j*16 + lr];
            *(bfx8*)&wp[((256 + j*64 + lane)) * 8] = v;
        }
    }
}

// Single barrier per tile. Buffer slots: sf/sh2 x2, sseg x3 (scan reads one
// phase later than sf/sh2 reads; max wave skew is 1 barrier).
__global__ __launch_bounds__(BLOCK, 3) void mlp_seg_mfma(
    const float* __restrict__ f, const int* __restrict__ seg,
    const __bf16* __restrict__ wp,
    const float* __restrict__ b1, const float* __restrict__ b2,
    const float* __restrict__ b3,
    float* __restrict__ sums, float* __restrict__ counts,
    int N, int ntiles)
{
    __shared__ __align__(16) __bf16 sf [2][RT * 64]; // 16 KB
    __shared__ __align__(16) __bf16 sh1[RT * 32];    // 4 KB (wave-private rows)
    __shared__ __align__(16) __bf16 sh2[2][RT * 64]; // 16 KB
    __shared__ __align__(16) int sseg3[3][RT];       // 768 B

    const int tid  = threadIdx.x;
    const int wv   = tid >> 6;
    const int lane = tid & 63;
    const int lr   = lane & 15;
    const int quad = lane >> 4;
    const int m0   = wv * 16;          // this wave's 16-row slice for L1/L2
    const int ar   = m0 + lr;          // data row for this lane (L1/L2)

    // ---- weight fragments: ONE dwordx4 each from repacked table, PINNED ----
    const bfx8* wpf = (const bfx8*)wp;
    bfx8 fw1[2][2], fw2[4], fw3[2][2];
    #pragma unroll
    for (int j = 0; j < 2; ++j)
        #pragma unroll
        for (int ks = 0; ks < 2; ++ks) {
            fw1[j][ks] = wpf[(j*2 + ks)*64 + lane];             PIN(fw1[j][ks]);
        }
    #pragma unroll
    for (int j = 0; j < 4; ++j) { fw2[j] = wpf[256 + j*64 + lane]; PIN(fw2[j]); }
    #pragma unroll
    for (int j = 0; j < 2; ++j)
        #pragma unroll
        for (int ks = 0; ks < 2; ++ks) {
            fw3[j][ks] = wpf[512 + ((wv*2 + j)*2 + ks)*64 + lane]; PIN(fw3[j][ks]);
        }

    // biases: direct 16B-aligned float4 loads, pinned.
    // swapped-D layout: feature = j*16 + quad*4 + rg
    fx4 rb1v[2], rb2v[4];
    #pragma unroll
    for (int j = 0; j < 2; ++j) { rb1v[j] = *(const fx4*)&b1[j*16 + quad*4]; PIN(rb1v[j]); }
    #pragma unroll
    for (int j = 0; j < 4; ++j) { rb2v[j] = *(const fx4*)&b2[j*16 + quad*4]; PIN(rb2v[j]); }
    float rb3[2];                      // folded in at flush time (run_len * b3)
    #pragma unroll
    for (int j = 0; j < 2; ++j) { rb3[j] = b3[wv*32 + j*16 + lr]; PIN(rb3[j]); }

    // ---- persistent segment-run state: lane owns cols {col0, col0+16},
    //      rows mt*16+quad*4+rg (16 rows/tile, increasing order) ----
    const int  col0    = wv*32 + lr;
    const bool cntlane = (wv == 0) && (lr == 0);
    int   cur_seg = -1;
    float rs0 = 0.f, rs1 = 0.f;
    int   rlen = 0;

    // ---- balanced contiguous tile ranges over persistent blocks ----
    const int nb   = gridDim.x;
    const int bb   = blockIdx.x;
    const int base = ntiles / nb, rem = ntiles % nb;
    const int tstart = bb * base + min(bb, rem);
    const int cnt    = base + (bb < rem ? 1 : 0);

    // ---- prologue: stage tile tstart into slot 0 ----
    if (cnt > 0) {
        const int R0 = tstart * RT;
        const float4* f4 = (const float4*)f + (size_t)R0 * 16;
        #pragma unroll
        for (int i = 0; i < 4; ++i) {
            const int idx4 = tid + i * 256;
            float4 qq = make_float4(0.f, 0.f, 0.f, 0.f);
            if ((size_t)R0 * 64 + (size_t)idx4 * 4 < (size_t)N * 64) qq = f4[idx4];
            const int r = idx4 >> 4;
            const int c = (idx4 & 15) * 4;
            bfx4 v;
            v[0] = (__bf16)qq.x; v[1] = (__bf16)qq.y;
            v[2] = (__bf16)qq.z; v[3] = (__bf16)qq.w;
            *(bfx4*)&sf[0][r*64 + (((c >> 3) ^ (r & 7)) << 3) + (c & 7)] = v;
        }
        if (tid < RT) sseg3[0][tid] = (R0 + tid < N) ? seg[R0 + tid] : -2;
    }
    __syncthreads();

    int p3 = 0;                        // sseg slot for current tile
    for (int i = 0; i < cnt; ++i) {
        const int t  = tstart + i;
        const int p2 = i & 1;
        const int p3n = (p3 + 1 == 3) ? 0 : p3 + 1;
        const bool havenext = (i + 1 < cnt);

        // ---- issue next tile's global loads EARLY ----
        float4 q[4];
        int rseg = -2;
        if (havenext) {
            const int Rn = (t + 1) * RT;
            const float4* f4n = (const float4*)f + (size_t)Rn * 16;
            #pragma unroll
            for (int k = 0; k < 4; ++k) {
                const int idx4 = tid + k * 256;
                q[k] = make_float4(0.f, 0.f, 0.f, 0.f);
                if ((size_t)Rn * 64 + (size_t)idx4 * 4 < (size_t)N * 64)
                    q[k] = f4n[idx4];
            }
            if (tid < RT) rseg = (Rn + tid < N) ? seg[Rn + tid] : -2;
        }

        // ---- L1: h1^T = W1^T * f^T (swapped), rows m0..m0+15 ----
        fx4 acc1[2] = {{0,0,0,0},{0,0,0,0}};
        #pragma unroll
        for (int ks = 0; ks < 2; ++ks) {
            bfx8 a = *(const bfx8*)&sf[p2][ar*64 + (((ks*4 + quad) ^ (ar & 7)) << 3)];
            #pragma unroll
            for (int j = 0; j < 2; ++j)
                acc1[j] = __builtin_amdgcn_mfma_f32_16x16x32_bf16(fw1[j][ks], a, acc1[j], 0, 0, 0);
        }
        #pragma unroll
        for (int j = 0; j < 2; ++j) {
            bfx4 w;
            #pragma unroll
            for (int rg = 0; rg < 4; ++rg)
                w[rg] = (__bf16)fmaxf(acc1[j][rg] + rb1v[j][rg], 0.f);
            const int b = j*2 + (quad >> 1);
            *(bfx4*)&sh1[ar*32 + ((b ^ (ar & 3)) << 3) + (quad & 1)*4] = w;
        }
        // no barrier: sh1 rows [m0, m0+16) written and read by this wave only

        // ---- L2: h2^T = W2^T * h1^T (swapped), K=32 ----
        fx4 acc2[4] = {{0,0,0,0},{0,0,0,0},{0,0,0,0},{0,0,0,0}};
        {
            bfx8 a = *(const bfx8*)&sh1[ar*32 + ((quad ^ (ar & 3)) << 3)];
            #pragma unroll
            for (int j = 0; j < 4; ++j)
                acc2[j] = __builtin_amdgcn_mfma_f32_16x16x32_bf16(fw2[j], a, acc2[j], 0, 0, 0);
        }
        #pragma unroll
        for (int j = 0; j < 4; ++j) {
            bfx4 w;
            #pragma unroll
            for (int rg = 0; rg < 4; ++rg)
                w[rg] = (__bf16)fmaxf(acc2[j][rg] + rb2v[j][rg], 0.f);
            const int b = j*2 + (quad >> 1);
            *(bfx4*)&sh2[p2][ar*64 + ((b ^ (ar & 7)) << 3) + (quad & 1)*4] = w;
        }

        // ---- stage next tile (pre-barrier; vmcnt waits inserted on q use) ----
        if (havenext) {
            #pragma unroll
            for (int k = 0; k < 4; ++k) {
                const int idx4 = tid + k * 256;
                const int r = idx4 >> 4;
                const int c = (idx4 & 15) * 4;
                bfx4 v;
                v[0] = (__bf16)q[k].x; v[1] = (__bf16)q[k].y;
                v[2] = (__bf16)q[k].z; v[3] = (__bf16)q[k].w;
                *(bfx4*)&sf[p2 ^ 1][r*64 + (((c >> 3) ^ (r & 7)) << 3) + (c & 7)] = v;
            }
            if (tid < RT) sseg3[p3n][tid] = rseg;
        }

        BAR_LGKM();   // sh2 + next-sf + next-sseg visible; ONLY barrier per tile

        // ---- L3: wave-owned 32-col slab over ALL 64 rows; acc3 stays live ----
        fx4 acc3[4][2];
        #pragma unroll
        for (int mt = 0; mt < 4; ++mt) {
            acc3[mt][0] = (fx4){0,0,0,0};
            acc3[mt][1] = (fx4){0,0,0,0};
            const int arow = mt*16 + lr;
            #pragma unroll
            for (int ks = 0; ks < 2; ++ks) {
                bfx8 a = *(const bfx8*)&sh2[p2][arow*64 + (((ks*4 + quad) ^ (arow & 7)) << 3)];
                #pragma unroll
                for (int j = 0; j < 2; ++j)
                    acc3[mt][j] = __builtin_amdgcn_mfma_f32_16x16x32_bf16(a, fw3[j][ks], acc3[mt][j], 0, 0, 0);
            }
        }

        // ---- segment scan DIRECTLY from registers (f32, no LDS round-trip).
        //      Lane's rows: mt*16 + quad*4 + rg, increasing; sorted seg ids
        //      => per-lane subsequence sorted; partial runs merge via atomics.
        #pragma unroll
        for (int mt = 0; mt < 4; ++mt) {
            const int4 s4 = *(const int4*)&sseg3[p3][mt*16 + quad*4];
            const int ss[4] = {s4.x, s4.y, s4.z, s4.w};
            #pragma unroll
            for (int rg = 0; rg < 4; ++rg) {
                const int s = ss[rg];
                if (s != cur_seg) {
                    if (cur_seg >= 0) {
                        atomicAdd(&sums[(size_t)cur_seg * D_OUT + col0],      rs0 + (float)rlen * rb3[0]);
                        atomicAdd(&sums[(size_t)cur_seg * D_OUT + col0 + 16], rs1 + (float)rlen * rb3[1]);
                        if (cntlane) atomicAdd(&counts[cur_seg], (float)rlen);
                    }
                    cur_seg = s; rs0 = 0.f; rs1 = 0.f; rlen = 0;
                }
                rs0 += acc3[mt][0][rg];
                rs1 += acc3[mt][1][rg];
                ++rlen;
            }
        }
        p3 = p3n;
    }

    if (cur_seg >= 0) {
        atomicAdd(&sums[(size_t)cur_seg * D_OUT + col0],      rs0 + (float)rlen * rb3[0]);
        atomicAdd(&sums[(size_t)cur_seg * D_OUT + col0 + 16], rs1 + (float)rlen * rb3[1]);
        if (cntlane) atomicAdd(&counts[cur_seg], (float)rlen);
    }
}

__global__ __launch_bounds__(256) void div_kernel(
    const float* __restrict__ sums, const float* __restrict__ counts,
    float* __restrict__ out, int total)
{
    const int i = blockIdx.x * 256 + threadIdx.x;
    if (i < total) out[i] = sums[i] / fmaxf(counts[i >> 7], 1.f);
}

extern "C" void kernel_launch(void* const* d_in, const int* in_sizes, int n_in,
                              void* d_out, int out_size, void* d_ws, size_t ws_size,
                              hipStream_t stream) {
    const float* f   = (const float*)d_in[0];
    const int*   seg = (const int*)  d_in[1];
    const float* W1 = (const float*)d_in[3];
    const float* b1 = (const float*)d_in[4];
    const float* W2 = (const float*)d_in[5];
    const float* b2 = (const float*)d_in[6];
    const float* W3 = (const float*)d_in[7];
    const float* b3 = (const float*)d_in[8];
    float* out = (float*)d_out;

    const int N = in_sizes[0] / D_IN;

    float*  sums   = (float*)d_ws;                  // [NSEG * D_OUT]
    float*  counts = sums + (size_t)NSEG * D_OUT;   // [NSEG]
    __bf16* wpack  = (__bf16*)(counts + NSEG);      // [1536 * 8] repacked weights (24 KB)

    hipMemsetAsync(d_ws, 0, ((size_t)NSEG * D_OUT + NSEG) * sizeof(float), stream);

    repack_w<<<1, 256, 0, stream>>>(W1, W2, W3, wpack);

    const int ntiles  = (N + RT - 1) / RT;
    const int nblocks = min(NB, ntiles);
    mlp_seg_mfma<<<nblocks, BLOCK, 0, stream>>>(f, seg, wpack, b1, b2, b3,
                                                sums, counts, N, ntiles);

    const int total = NSEG * D_OUT;
    div_kernel<<<(total + 255) / 256, 256, 0, stream>>>(sums, counts, out, total);
}